// Round 7
// baseline (337.832 us; speedup 1.0000x reference)
//
#include <hip/hip_runtime.h>
#include <math.h>

// Problem constants (fixed by setup_inputs)
#define NROWS 32768   // 32 * 32 * 32
#define DIMS  256
#define KCODES 1024

typedef __attribute__((ext_vector_type(8))) short short8;   // 8 bf16 = 4 VGPRs
typedef __attribute__((ext_vector_type(4))) float f32x4;    // MFMA C/D & NT stores

// ws layout (float offsets)
static const size_t OFF_FLAT   = 0;                      // [32768][256] fp32 rows
static const size_t OFF_WB     = 8388608;                // [1024][256] bf16, MFMA-fragment tile order
static const size_t OFF_WNORM  = OFF_WB + 131072;        // [1024]
static const size_t OFF_ENCSUM = OFF_WNORM + 1024;       // [1024]
static const size_t OFF_LOSSP  = OFF_ENCSUM + 1024;      // [512]

// out layout (float offsets): loss | quantized NCHW | perplexity | encodings
static const size_t OUT_Q    = 1;
static const size_t OUT_PERP = 8388609;
static const size_t OUT_ENC  = 8388610;

__device__ inline unsigned short f2bf(float f) {
    unsigned int u = __float_as_uint(f);
    unsigned int r = u + 0x7FFFu + ((u >> 16) & 1u);   // RNE
    return (unsigned short)(r >> 16);
}

// pack distance (fp32, low 10 mantissa bits cleared) with 10-bit code index.
__device__ inline float packdi(float d, int code) {
    return __uint_as_float((__float_as_uint(d) & 0xFFFFFC00u) | (unsigned)code);
}

// ---------------- W prep: bf16 fragment-order layout + wnorm + zero accum ----
// Tile tt = code>>4 (16 codes). Element (code, dim): col=code&15, kk=dim>>5,
// quad=(dim>>3)&3, j=dim&7 at tt*4096 + ((kk*4+quad)*16 + col)*8 + j.
__global__ __launch_bounds__(256) void wprep(const float* __restrict__ Wm,
                                             unsigned short* __restrict__ Wb,
                                             float* __restrict__ wnorm,
                                             float* __restrict__ enc_sum,
                                             float* __restrict__ loss_part)
{
    const int r = blockIdx.x * 4 + (threadIdx.x >> 6);
    const int lane = threadIdx.x & 63;
    float4 v = ((const float4*)(Wm + (size_t)r * 256))[lane];
    ushort4 o;
    o.x = f2bf(v.x); o.y = f2bf(v.y); o.z = f2bf(v.z); o.w = f2bf(v.w);
    const int d0 = lane * 4;
    const int kk = d0 >> 5, quad = (d0 >> 3) & 3, jb = d0 & 7;
    const int tt = r >> 4, col = r & 15;
    const size_t idx = (size_t)tt * 4096 + (size_t)((kk * 4 + quad) * 16 + col) * 8 + jb;
    *(ushort4*)(Wb + idx) = o;
    float s = v.x*v.x + v.y*v.y + v.z*v.z + v.w*v.w;
    #pragma unroll
    for (int off = 32; off > 0; off >>= 1) s += __shfl_down(s, off);
    if (lane == 0) wnorm[r] = s;
    if (blockIdx.x == 0) {
        #pragma unroll
        for (int q = 0; q < 4; ++q) enc_sum[threadIdx.x * 4 + q] = 0.0f;
    }
    if (blockIdx.x < 2) loss_part[blockIdx.x * 256 + threadIdx.x] = 0.0f;
}

// ---------------- megakernel: transpose + MFMA GEMM + topk + refine + outputs --
// grid 512 (b = blk>>4, hw0 = (blk&15)*64), block 512 = 8 waves:
// row-group g = wave&3 (16 rows), code-half h = wave>>2 (512 codes).
__global__ __launch_bounds__(512, 4) void mega(
    const float* __restrict__ x, const float* __restrict__ Wm,
    const unsigned short* __restrict__ Wb, const float* __restrict__ wnorm,
    float* __restrict__ flat, float* __restrict__ enc_sum,
    float* __restrict__ enc, float* __restrict__ outq,
    float* __restrict__ loss_part)
{
    __shared__ __align__(16) char lds[65536];
    float* xt   = (float*)lds;                 // [256][64] fp32 (P1, P4)
    float* sCd  = (float*)lds;                 // [64][96] packed (P2b)
    int*   mIdx = (int*)(lds + 24576);         // [64][8]
    int*   sI0  = (int*)(lds + 26624);         // [64]
    int*   sI1  = (int*)(lds + 26880);         // [64]
    float* sW0  = (float*)(lds + 27136);       // [64]
    float* sW1  = (float*)(lds + 27392);       // [64]

    const int t    = threadIdx.x;
    const int wave = t >> 6;
    const int g    = wave & 3;
    const int h    = wave >> 2;
    const int lane = t & 63;
    const int col  = lane & 15;
    const int quad = lane >> 4;
    const int b    = blockIdx.x >> 4;
    const int hw0  = (blockIdx.x & 15) * 64;
    const int r0   = blockIdx.x * 64;          // = b*1024 + hw0

    // ---- P1: coalesced NCHW load -> xt [c][hw] ----
    #pragma unroll
    for (int p = 0; p < 8; ++p) {
        int lin = p * 512 + t;
        int c = lin >> 4, hw4 = lin & 15;
        f32x4 v = *(const f32x4*)(x + ((size_t)(b * 256 + c)) * 1024 + hw0 + hw4 * 4);
        *(f32x4*)(xt + c * 64 + hw4 * 4) = v;
    }
    __syncthreads();

    // ---- P1b: write flat rows (row-major) from xt ----
    {
        const int r = t >> 3, j = t & 7;
        float* fr = flat + (size_t)(r0 + r) * 256;
        #pragma unroll
        for (int p = 0; p < 8; ++p) {
            f32x4 v;
            #pragma unroll
            for (int k = 0; k < 4; ++k) v[k] = xt[(p * 32 + j * 4 + k) * 64 + r];
            *(f32x4*)(fr + p * 32 + j * 4) = v;
        }
    }
    __syncthreads();   // flat complete; xt dead

    // ---- P1c: A fragments from flat (fp32 -> bf16) ----
    short8 af[8];
    {
        const float* arow = flat + (size_t)(r0 + g * 16 + col) * 256 + quad * 8;
        #pragma unroll
        for (int kk = 0; kk < 8; ++kk) {
            float4 u = *(const float4*)(arow + kk * 32);
            float4 v = *(const float4*)(arow + kk * 32 + 4);
            short8 f;
            f[0] = (short)f2bf(u.x); f[1] = (short)f2bf(u.y);
            f[2] = (short)f2bf(u.z); f[3] = (short)f2bf(u.w);
            f[4] = (short)f2bf(v.x); f[5] = (short)f2bf(v.y);
            f[6] = (short)f2bf(v.z); f[7] = (short)f2bf(v.w);
            af[kk] = f;
        }
    }

    // ---- P2: register GEMM, 32 tiles of 16 codes, depth-1 ping-pong prefetch ----
    float m0[4], m1[4], m2[4];
    #pragma unroll
    for (int r = 0; r < 4; ++r) { m0[r] = 3.4e38f; m1[r] = 3.4e38f; m2[r] = 3.4e38f; }

    const unsigned short* bb = Wb + (size_t)h * 131072 + (size_t)lane * 8;
    short8 bufA[8], bufB[8];
    #pragma unroll
    for (int kk = 0; kk < 8; ++kk) bufA[kk] = *(const short8*)(bb + kk * 512);

    #define TOPK_UPD(ACC, CODE) {                                              \
        float wn = wnorm[(CODE)];                                              \
        _Pragma("unroll")                                                      \
        for (int r = 0; r < 4; ++r) {                                          \
            float pv = packdi(fmaf(-2.0f, (ACC)[r], wn), (CODE));              \
            float t0 = fmaxf(m0[r], pv); m0[r] = fminf(m0[r], pv);             \
            float t1 = fmaxf(m1[r], t0); m1[r] = fminf(m1[r], t0);             \
            m2[r] = fminf(m2[r], t1);                                          \
        } }

    for (int cc2 = 0; cc2 < 16; ++cc2) {
        const unsigned short* p1 = bb + (size_t)(2 * cc2 + 1) * 4096;
        #pragma unroll
        for (int kk = 0; kk < 8; ++kk) bufB[kk] = *(const short8*)(p1 + kk * 512);
        f32x4 acc = {0.f, 0.f, 0.f, 0.f};
        #pragma unroll
        for (int kk = 0; kk < 8; ++kk)
            acc = __builtin_amdgcn_mfma_f32_16x16x32_bf16(af[kk], bufA[kk], acc, 0, 0, 0);
        TOPK_UPD(acc, h * 512 + (2 * cc2) * 16 + col);
        if (cc2 < 15) {
            const unsigned short* p2 = bb + (size_t)(2 * cc2 + 2) * 4096;
            #pragma unroll
            for (int kk = 0; kk < 8; ++kk) bufA[kk] = *(const short8*)(p2 + kk * 512);
        }
        f32x4 acc2 = {0.f, 0.f, 0.f, 0.f};
        #pragma unroll
        for (int kk = 0; kk < 8; ++kk)
            acc2 = __builtin_amdgcn_mfma_f32_16x16x32_bf16(af[kk], bufB[kk], acc2, 0, 0, 0);
        TOPK_UPD(acc2, h * 512 + (2 * cc2 + 1) * 16 + col);
    }
    #undef TOPK_UPD
    __syncthreads();   // xt reads long done; sCd region free

    // ---- P2b: dump candidates, merge top-8 per row ----
    #pragma unroll
    for (int r = 0; r < 4; ++r) {
        int rl = g * 16 + quad * 4 + r;
        sCd[rl * 96 + h * 48 + col * 3 + 0] = m0[r];
        sCd[rl * 96 + h * 48 + col * 3 + 1] = m1[r];
        sCd[rl * 96 + h * 48 + col * 3 + 2] = m2[r];
    }
    __syncthreads();

    if (t < 64) {
        float bd[8];
        #pragma unroll
        for (int q = 0; q < 8; ++q) bd[q] = 3.4e38f;
        for (int s = 0; s < 96; ++s) {
            float d = sCd[t * 96 + s];
            if (d < bd[7]) {
                bd[7] = d;
                #pragma unroll
                for (int p = 7; p > 0; --p) {
                    if (bd[p] < bd[p-1]) { float tf = bd[p]; bd[p] = bd[p-1]; bd[p-1] = tf; }
                }
            }
        }
        #pragma unroll
        for (int q = 0; q < 8; ++q)
            mIdx[t * 8 + q] = (int)(__float_as_uint(bd[q]) & 1023u);
    }
    __syncthreads();

    // ---- P3: fp64 refine. thread = (row = t>>3, dim-chunk j = t&7). ----
    const int rr = t >> 3, jj = t & 7;
    float xr[32];
    {
        const float* fr = flat + (size_t)(r0 + rr) * 256;
        #pragma unroll
        for (int p = 0; p < 8; ++p) {
            f32x4 v = *(const f32x4*)(fr + p * 32 + jj * 4);
            xr[p*4+0] = v[0]; xr[p*4+1] = v[1]; xr[p*4+2] = v[2]; xr[p*4+3] = v[3];
        }
    }
    double rnp = 0.0;
    #pragma unroll
    for (int k = 0; k < 32; ++k) rnp += (double)xr[k] * (double)xr[k];
    rnp += __shfl_down(rnp, 4); rnp += __shfl_down(rnp, 2); rnp += __shfl_down(rnp, 1);

    double d0 = 1e300, d1 = 1e300; int c0i = 1 << 30, c1i = 1 << 30;
    for (int q = 0; q < 8; ++q) {
        const int c = mIdx[rr * 8 + q];
        const float* wr = Wm + (size_t)c * 256;
        double dotp = 0.0, wnp = 0.0;
        #pragma unroll
        for (int p = 0; p < 8; ++p) {
            f32x4 wv = *(const f32x4*)(wr + p * 32 + jj * 4);
            #pragma unroll
            for (int k = 0; k < 4; ++k) {
                dotp += (double)xr[p*4+k] * (double)wv[k];
                wnp  += (double)wv[k] * (double)wv[k];
            }
        }
        double dd = wnp - 2.0 * dotp;
        dd += __shfl_down(dd, 4); dd += __shfl_down(dd, 2); dd += __shfl_down(dd, 1);
        if (dd < d0 || (dd == d0 && c < c0i)) { d1 = d0; c1i = c0i; d0 = dd; c0i = c; }
        else if (dd < d1 || (dd == d1 && c < c1i)) { d1 = dd; c1i = c; }
    }
    if (jj == 0) {
        double D0 = rnp + d0;
        double D1 = rnp + d1;
        double inv0 = 1.0 / D0, inv1 = 1.0 / D1;
        double nrm = sqrt(inv0 * inv0 + inv1 * inv1);
        if (nrm < 1e-12) nrm = 1e-12;
        float w0 = (float)(inv0 / nrm);
        float w1 = (float)(inv1 / nrm);
        sI0[rr] = c0i; sI1[rr] = c1i;
        sW0[rr] = w0;  sW1[rr] = w1;
        atomicAdd(&enc_sum[c0i], w0);
        atomicAdd(&enc_sum[c1i], w1);
    }
    __syncthreads();

    // ---- P4a: encodings rows (wave w handles rows w*8..w*8+7), NT coalesced ----
    #pragma unroll
    for (int rl = 0; rl < 8; ++rl) {
        int rowl = wave * 8 + rl;
        int i0 = sI0[rowl], i1 = sI1[rowl];
        float w0 = sW0[rowl], w1 = sW1[rowl];
        float* dst = enc + (size_t)(r0 + rowl) * KCODES;
        #pragma unroll
        for (int it = 0; it < 4; ++it) {
            int base = it * 256 + lane * 4;
            f32x4 v;
            v.x = (base + 0 == i0) ? w0 : ((base + 0 == i1) ? w1 : 0.0f);
            v.y = (base + 1 == i0) ? w0 : ((base + 1 == i1) ? w1 : 0.0f);
            v.z = (base + 2 == i0) ? w0 : ((base + 2 == i1) ? w1 : 0.0f);
            v.w = (base + 3 == i0) ? w0 : ((base + 3 == i1) ? w1 : 0.0f);
            __builtin_nontemporal_store(v, (f32x4*)(dst + it * 256 + lane * 4));
        }
    }

    // ---- P4b: quantize own (row, chunk), loss, q -> LDS [c][hw] ----
    const int qi0 = sI0[rr], qi1 = sI1[rr];
    const float qw0 = sW0[rr], qw1 = sW1[rr];
    __syncthreads();   // sI/sW reads done before xt overwrite
    float ls = 0.0f;
    {
        const float* wa = Wm + (size_t)qi0 * 256;
        const float* wb = Wm + (size_t)qi1 * 256;
        #pragma unroll
        for (int p = 0; p < 8; ++p) {
            f32x4 av = *(const f32x4*)(wa + p * 32 + jj * 4);
            f32x4 bv = *(const f32x4*)(wb + p * 32 + jj * 4);
            #pragma unroll
            for (int k = 0; k < 4; ++k) {
                float qv = qw0 * av[k] + qw1 * bv[k];
                float d = qv - xr[p*4+k];
                ls += d * d;
                xt[(p * 32 + jj * 4 + k) * 64 + rr] = qv;
            }
        }
    }
    #pragma unroll
    for (int off = 32; off > 0; off >>= 1) ls += __shfl_down(ls, off);
    if (lane == 0) atomicAdd(&loss_part[blockIdx.x], ls);
    __syncthreads();

    // ---- P4c: coalesced NCHW write of quantized ----
    #pragma unroll
    for (int p = 0; p < 8; ++p) {
        int lin = p * 512 + t;
        int c = lin >> 4, hw4 = lin & 15;
        f32x4 v = *(const f32x4*)(xt + c * 64 + hw4 * 4);
        __builtin_nontemporal_store(v,
            (f32x4*)(outq + ((size_t)(b * 256 + c)) * 1024 + hw0 + hw4 * 4));
    }
}

// ---------------- finalize: loss + perplexity ----------------
__global__ __launch_bounds__(256) void finalize_k(const float* __restrict__ enc_sum,
                                                  const float* __restrict__ loss_part,
                                                  float* __restrict__ out)
{
    __shared__ double sh[256];
    const int t = threadIdx.x;
    double ls = 0.0;
    for (int i = t; i < 512; i += 256) ls += (double)loss_part[i];
    sh[t] = ls; __syncthreads();
    for (int s = 128; s > 0; s >>= 1) { if (t < s) sh[t] += sh[t + s]; __syncthreads(); }
    double loss_sum = sh[0];
    __syncthreads();
    double ps = 0.0;
    for (int k = t; k < KCODES; k += 256) {
        double p = (double)enc_sum[k] / (double)NROWS;
        ps += p * log(p + 1e-10);
    }
    sh[t] = ps; __syncthreads();
    for (int s = 128; s > 0; s >>= 1) { if (t < s) sh[t] += sh[t + s]; __syncthreads(); }
    if (t == 0) {
        out[0]        = (float)(1.25 * loss_sum / 8388608.0);
        out[OUT_PERP] = (float)exp(-sh[0]);
    }
}

extern "C" void kernel_launch(void* const* d_in, const int* in_sizes, int n_in,
                              void* d_out, int out_size, void* d_ws, size_t ws_size,
                              hipStream_t stream)
{
    const float* x  = (const float*)d_in[0];
    const float* Wm = (const float*)d_in[1];
    float* out = (float*)d_out;
    float* ws  = (float*)d_ws;

    float*          flat    = ws + OFF_FLAT;
    unsigned short* Wb      = (unsigned short*)(ws + OFF_WB);
    float*          wnorm   = ws + OFF_WNORM;
    float*          enc_sum = ws + OFF_ENCSUM;
    float*          loss_p  = ws + OFF_LOSSP;

    wprep<<<KCODES / 4, 256, 0, stream>>>(Wm, Wb, wnorm, enc_sum, loss_p);
    mega<<<NROWS / 64, 512, 0, stream>>>(x, Wm, Wb, wnorm, flat, enc_sum,
                                         out + OUT_ENC, out + OUT_Q, loss_p);
    finalize_k<<<1, 256, 0, stream>>>(enc_sum, loss_p, out);
}